// Round 2
// baseline (516.094 us; speedup 1.0000x reference)
//
#include <hip/hip_runtime.h>
#include <stdint.h>

#define BATCH  2048
#define HID    512
#define CAP    65536
#define NHASH  8
#define TOPK   32
#define NSLICE 16
#define SLICE_SZ (CAP / NSLICE)   // 4096

typedef unsigned int   u32;
typedef unsigned long long u64;

// ---------------------------------------------------------------------------
// K1: Psum[h][n] = sum_d P[n][h][d] in f64 (exact enough), stored f64 [h][n]
// ---------------------------------------------------------------------------
__global__ __launch_bounds__(256) void k_psum(const float* __restrict__ proj,
                                              double* __restrict__ psumT) {
    int h = blockIdx.x * blockDim.x + threadIdx.x;
    if (h >= HID) return;
    for (int n = 0; n < NHASH; n++) {
        const float* p = proj + ((size_t)n * HID + h) * 16;
        double s = 0.0;
        #pragma unroll
        for (int d = 0; d < 16; d++) s += (double)p[d];
        psumT[(size_t)h * NHASH + n] = s;
    }
}

// ---------------------------------------------------------------------------
// K2: hash bytes for rows of x (wave per row, grid-stride). f64 accumulation
// of exact f32 products -> effectively exact sign decision vs f64 reference.
// Optionally accumulates 16-slice x 256-bucket histogram (keys only).
// ---------------------------------------------------------------------------
__global__ void k_hash(const float* __restrict__ x, int rows,
                       const double* __restrict__ psumT,
                       unsigned char* __restrict__ outb,
                       u32* __restrict__ hist16, int do_hist) {
    int lane = threadIdx.x & 63;
    int wave = (int)((blockIdx.x * blockDim.x + threadIdx.x) >> 6);
    int nwaves = (int)((gridDim.x * blockDim.x) >> 6);

    double ps[8][8];  // [j][n] for h = lane*8 + j
    #pragma unroll
    for (int j = 0; j < 8; j++) {
        #pragma unroll
        for (int n = 0; n < 8; n++)
            ps[j][n] = psumT[(size_t)(lane * 8 + j) * NHASH + n];
    }

    for (int r = wave; r < rows; r += nwaves) {
        const float4* xp = (const float4*)(x + (size_t)r * HID + lane * 8);
        float4 a = xp[0], b4 = xp[1];
        float xf[8] = {a.x, a.y, a.z, a.w, b4.x, b4.y, b4.z, b4.w};
        double dn[8];
        #pragma unroll
        for (int n = 0; n < 8; n++) dn[n] = 0.0;
        #pragma unroll
        for (int j = 0; j < 8; j++) {
            double xd = (double)xf[j];
            #pragma unroll
            for (int n = 0; n < 8; n++) dn[n] = fma(xd, ps[j][n], dn[n]);
        }
        #pragma unroll
        for (int s = 32; s >= 1; s >>= 1) {
            #pragma unroll
            for (int n = 0; n < 8; n++) dn[n] += __shfl_xor(dn[n], s, 64);
        }
        u32 byte = 0;
        #pragma unroll
        for (int n = 0; n < 8; n++) if (dn[n] > 0.0) byte |= (1u << n);
        if (lane == 0) {
            outb[r] = (unsigned char)byte;
            if (do_hist) atomicAdd(&hist16[(r / SLICE_SZ) * 256 + byte], 1u);
        }
    }
}

// ---------------------------------------------------------------------------
// K3: prefix sums: bucketCnt, bucketOff (exclusive over buckets),
// off16[s][v] = bucketOff[v] + sum_{s'<s} hist16[s'][v]
// ---------------------------------------------------------------------------
__global__ __launch_bounds__(256) void k_scan(const u32* __restrict__ hist16,
                                              u32* __restrict__ bucketCnt,
                                              u32* __restrict__ bucketOff,
                                              u32* __restrict__ off16) {
    __shared__ u32 sh[256], sh2[256];
    int v = threadIdx.x;
    u32 tot = 0;
    for (int s = 0; s < NSLICE; s++) tot += hist16[s * 256 + v];
    bucketCnt[v] = tot;
    sh[v] = tot;
    __syncthreads();
    if (v == 0) {
        u32 run = 0;
        for (int u = 0; u < 256; u++) { sh2[u] = run; run += sh[u]; }
    }
    __syncthreads();
    u32 base = sh2[v];
    bucketOff[v] = base;
    for (int s = 0; s < NSLICE; s++) { off16[s * 256 + v] = base; base += hist16[s * 256 + v]; }
}

// ---------------------------------------------------------------------------
// K4: stable compaction: bucketList sorted by (hash byte, index ascending).
// block = (bucket_group of 4, slice); wave per bucket; ballot-rank writes.
// ---------------------------------------------------------------------------
__global__ __launch_bounds__(256) void k_compact(const unsigned char* __restrict__ khash,
                                                 const u32* __restrict__ off16,
                                                 u32* __restrict__ bucketList) {
    __shared__ unsigned char sh[SLICE_SZ];
    int s  = blockIdx.x & (NSLICE - 1);
    int bg = blockIdx.x >> 4;
    ((uint4*)sh)[threadIdx.x] = ((const uint4*)(khash + (size_t)s * SLICE_SZ))[threadIdx.x];
    __syncthreads();
    int w = threadIdx.x >> 6, lane = threadIdx.x & 63;
    int v = bg * 4 + w;
    u32 base = off16[s * 256 + v];
    for (int i = 0; i < SLICE_SZ / 64; i++) {
        int c = i * 64 + lane;
        unsigned char byte = sh[c];
        bool hit = (byte == (unsigned char)v);
        u64 m = __ballot(hit);
        if (hit) {
            int rank = __popcll(m & ((1ull << lane) - 1ull));
            bucketList[base + rank] = (u32)(s * SLICE_SZ + c);
        }
        base += (u32)__popcll(m);
    }
}

// ---------------------------------------------------------------------------
// K5: per-query top-32 by (hamming distance, index). Wave per query.
// Order within the 32 is irrelevant downstream (attention is a set-reduce).
// ---------------------------------------------------------------------------
__global__ __launch_bounds__(256) void k_select(const unsigned char* __restrict__ qhash,
                                                const u32* __restrict__ bucketCnt,
                                                const u32* __restrict__ bucketOff,
                                                const u32* __restrict__ bucketList,
                                                int* __restrict__ topIdx) {
    __shared__ u32 sCnt[256], sOff[256];
    __shared__ int sPos[4];
    int tid = threadIdx.x;
    sCnt[tid] = bucketCnt[tid];
    sOff[tid] = bucketOff[tid];
    int w = tid >> 6, lane = tid & 63;
    if (lane == 0) sPos[w] = 0;
    __syncthreads();

    int q = blockIdx.x * 4 + w;
    u32 qh = qhash[q];

    int d[4]; u32 cnt[4], off[4];
    #pragma unroll
    for (int jj = 0; jj < 4; jj++) {
        int v = lane + jj * 64;
        d[jj] = __popc(qh ^ (u32)v);
        cnt[jj] = sCnt[v];
        off[jj] = sOff[v];
    }

    // counts per distance (wave-reduced; all lanes get totals)
    u32 ct[9];
    #pragma unroll
    for (int t = 0; t < 9; t++) {
        u32 c = 0;
        #pragma unroll
        for (int jj = 0; jj < 4; jj++) c += (d[jj] == t) ? cnt[jj] : 0u;
        #pragma unroll
        for (int s = 32; s >= 1; s >>= 1) c += __shfl_xor(c, s, 64);
        ct[t] = c;
    }

    int dcut = 0; u32 run = 0, before = 0;
    for (int t = 0; t < 9; t++) {
        before = run; run += ct[t];
        if (run >= TOPK) { dcut = t; break; }
    }
    int need = TOPK - (int)before;

    // Phase A: all entries of buckets with dist < dcut (total == before < 32)
    #pragma unroll
    for (int jj = 0; jj < 4; jj++) {
        if (d[jj] < dcut && cnt[jj] > 0) {
            int base = atomicAdd(&sPos[w], (int)cnt[jj]);
            for (u32 e = 0; e < cnt[jj]; e++)
                topIdx[q * TOPK + base + e] = (int)bucketList[off[jj] + e];
        }
    }

    // Phase B: lowest-index `need` among buckets at dist == dcut
    int nb = 0;
    #pragma unroll
    for (int jj = 0; jj < 4; jj++) nb += (d[jj] == dcut) ? 1 : 0;
    #pragma unroll
    for (int s = 32; s >= 1; s >>= 1) nb += __shfl_xor(nb, s, 64);

    if (nb == 1) {
        u32 boff = 0xFFFFFFFFu;
        #pragma unroll
        for (int jj = 0; jj < 4; jj++) if (d[jj] == dcut) boff = off[jj];
        #pragma unroll
        for (int s = 32; s >= 1; s >>= 1) boff = min(boff, __shfl_xor(boff, s, 64));
        if (lane < need)
            topIdx[q * TOPK + (int)before + lane] = (int)bucketList[boff + lane];
    } else {
        // k-way merge of sorted bucket lists (rare path)
        u32 pos[4], end[4]; int val[4];
        #pragma unroll
        for (int jj = 0; jj < 4; jj++) {
            if (d[jj] == dcut && cnt[jj] > 0) {
                pos[jj] = off[jj]; end[jj] = off[jj] + cnt[jj];
                val[jj] = (int)bucketList[pos[jj]];
            } else { pos[jj] = 0; end[jj] = 0; val[jj] = 0x7fffffff; }
        }
        for (int it = 0; it < need; it++) {
            int m = min(min(val[0], val[1]), min(val[2], val[3]));
            int g = m;
            #pragma unroll
            for (int s = 32; s >= 1; s >>= 1) g = min(g, __shfl_xor(g, s, 64));
            if (lane == 0) topIdx[q * TOPK + (int)before + it] = g;
            if (m == g && g != 0x7fffffff) {
                #pragma unroll
                for (int jj = 0; jj < 4; jj++) {
                    if (val[jj] == g) {
                        pos[jj]++;
                        val[jj] = (pos[jj] < end[jj]) ? (int)bucketList[pos[jj]] : 0x7fffffff;
                        break;
                    }
                }
            }
        }
    }
}

// ---------------------------------------------------------------------------
// K6: gather + scores + softmax + weighted V sum. Block per query.
// ---------------------------------------------------------------------------
__global__ __launch_bounds__(256) void k_attn(const float* __restrict__ keys,
                                              const float* __restrict__ vals,
                                              const float* __restrict__ query,
                                              const int* __restrict__ topIdx,
                                              float* __restrict__ mo) {
    __shared__ int sIdx[TOPK];
    __shared__ float sSc[TOPK], sE[TOPK];
    int b = blockIdx.x, tid = threadIdx.x;
    if (tid < TOPK) sIdx[tid] = topIdx[b * TOPK + tid];
    __syncthreads();

    int w = tid >> 6, lane = tid & 63;
    const float4* qp = (const float4*)(query + (size_t)b * HID + lane * 8);
    float4 qa = qp[0], qb = qp[1];

    for (int i = w * 8; i < w * 8 + 8; i++) {
        int idx = sIdx[i];
        const float4* kp = (const float4*)(keys + (size_t)idx * HID + lane * 8);
        float4 ka = kp[0], kb = kp[1];
        float dot = qa.x * ka.x + qa.y * ka.y + qa.z * ka.z + qa.w * ka.w
                  + qb.x * kb.x + qb.y * kb.y + qb.z * kb.z + qb.w * kb.w;
        #pragma unroll
        for (int s = 32; s >= 1; s >>= 1) dot += __shfl_xor(dot, s, 64);
        if (lane == 0) sSc[i] = dot * 0.04419417382415922f;  // 1/sqrt(512)
    }
    __syncthreads();

    if (tid < TOPK) {
        float m = -1e30f;
        for (int i = 0; i < TOPK; i++) m = fmaxf(m, sSc[i]);
        sE[tid] = expf(sSc[tid] - m);
    }
    __syncthreads();

    float sum = 0.f;
    for (int i = 0; i < TOPK; i++) sum += sE[i];
    float inv = 1.0f / sum;

    int h0 = tid, h1 = tid + 256;
    float a0 = 0.f, a1 = 0.f;
    for (int i = 0; i < TOPK; i++) {
        int idx = sIdx[i];
        float e = sE[i];
        a0 += e * vals[(size_t)idx * HID + h0];
        a1 += e * vals[(size_t)idx * HID + h1];
    }
    mo[(size_t)b * HID + h0] = a0 * inv;
    mo[(size_t)b * HID + h1] = a1 * inv;
}

// ---------------------------------------------------------------------------
// K7: transpose out_w [o][h] -> wt [h][o] for coalesced projection reads
// ---------------------------------------------------------------------------
__global__ __launch_bounds__(256) void k_transpose(const float* __restrict__ w,
                                                   float* __restrict__ wt) {
    __shared__ float tile[64][65];
    int bx = blockIdx.x, by = blockIdx.y;
    int tx = threadIdx.x & 63, ty = threadIdx.x >> 6;
    for (int r = ty; r < 64; r += 4)
        tile[r][tx] = w[(size_t)(by * 64 + r) * HID + bx * 64 + tx];
    __syncthreads();
    for (int r = ty; r < 64; r += 4)
        wt[(size_t)(bx * 64 + r) * HID + by * 64 + tx] = tile[tx][r];
}

// ---------------------------------------------------------------------------
// K8: out[b][o] = sum_h mo[b][h] * wt[h][o] + bias[o]; 8 b-rows per block.
// ---------------------------------------------------------------------------
__global__ __launch_bounds__(256) void k_proj(const float* __restrict__ mo,
                                              const float* __restrict__ wt,
                                              const float* __restrict__ bias,
                                              float* __restrict__ out) {
    int tid = threadIdx.x;
    int o = (blockIdx.x & 1) * 256 + tid;
    int bb = (blockIdx.x >> 1) * 8;
    float acc[8];
    #pragma unroll
    for (int r = 0; r < 8; r++) acc[r] = 0.f;
    for (int h = 0; h < HID; h++) {
        float wv = wt[(size_t)h * HID + o];
        #pragma unroll
        for (int r = 0; r < 8; r++)
            acc[r] += mo[(size_t)(bb + r) * HID + h] * wv;
    }
    float bv = bias[o];
    #pragma unroll
    for (int r = 0; r < 8; r++)
        out[(size_t)(bb + r) * HID + o] = acc[r] + bv;
}

// ---------------------------------------------------------------------------
extern "C" void kernel_launch(void* const* d_in, const int* in_sizes, int n_in,
                              void* d_out, int out_size, void* d_ws, size_t ws_size,
                              hipStream_t stream) {
    const float* query = (const float*)d_in[0];
    const float* keys  = (const float*)d_in[1];
    const float* vals  = (const float*)d_in[2];
    const float* proj  = (const float*)d_in[3];
    const float* outw  = (const float*)d_in[4];
    const float* outb  = (const float*)d_in[5];
    float* out = (float*)d_out;

    char* ws = (char*)d_ws;
    double*        psumT      = (double*)(ws + 0);              // 32 KB
    unsigned char* qhash      = (unsigned char*)(ws + 32768);   // 2 KB
    unsigned char* khash      = (unsigned char*)(ws + 34816);   // 64 KB
    u32*           hist16     = (u32*)(ws + 100352);            // 16 KB
    u32*           bucketCnt  = (u32*)(ws + 116736);            // 1 KB
    u32*           bucketOff  = (u32*)(ws + 117760);            // 1 KB
    u32*           off16      = (u32*)(ws + 118784);            // 16 KB
    u32*           bucketList = (u32*)(ws + 135168);            // 256 KB
    int*           topIdx     = (int*)(ws + 397312);            // 256 KB
    float*         mo         = (float*)(ws + 659456);          // 4 MB
    float*         wt         = (float*)(ws + 4853760);         // 1 MB
    (void)in_sizes; (void)n_in; (void)out_size; (void)ws_size;

    hipMemsetAsync(hist16, 0, 16384, stream);
    k_psum<<<2, 256, 0, stream>>>(proj, psumT);
    k_hash<<<256, 256, 0, stream>>>(query, BATCH, psumT, qhash, hist16, 0);
    k_hash<<<2048, 256, 0, stream>>>(keys, CAP, psumT, khash, hist16, 1);
    k_scan<<<1, 256, 0, stream>>>(hist16, bucketCnt, bucketOff, off16);
    k_compact<<<1024, 256, 0, stream>>>(khash, off16, bucketList);
    k_select<<<BATCH / 4, 256, 0, stream>>>(qhash, bucketCnt, bucketOff, bucketList, topIdx);
    k_attn<<<BATCH, 256, 0, stream>>>(keys, vals, query, topIdx, mo);
    k_transpose<<<dim3(8, 8), 256, 0, stream>>>(outw, wt);
    k_proj<<<512, 256, 0, stream>>>(mo, wt, outb, out);
}

// Round 4
// 392.442 us; speedup vs baseline: 1.3151x; 1.3151x over previous
//
#include <hip/hip_runtime.h>
#include <stdint.h>

#define BATCH  2048
#define HID    512
#define CAP    65536
#define NHASH  8
#define TOPK   32
#define NSLICE 16
#define SLICE_SZ (CAP / NSLICE)   // 4096
#define ROWS_TILE 16

typedef unsigned int   u32;
typedef unsigned long long u64;

// ---------------------------------------------------------------------------
// K1: Psum[h][n] = sum_d P[n][h][d] in f64, stored f64 [h][n]
// ---------------------------------------------------------------------------
__global__ __launch_bounds__(256) void k_psum(const float* __restrict__ proj,
                                              double* __restrict__ psumT) {
    int h = blockIdx.x * blockDim.x + threadIdx.x;
    if (h >= HID) return;
    for (int n = 0; n < NHASH; n++) {
        const float* p = proj + ((size_t)n * HID + h) * 16;
        double s = 0.0;
        #pragma unroll
        for (int d = 0; d < 16; d++) s += (double)p[d];
        psumT[(size_t)h * NHASH + n] = s;
    }
}

// ---------------------------------------------------------------------------
// K2: hash bytes. LDS-staged design: 16-row x-tile (32 KB, XOR-swizzled
// float4 columns) + Psum table (32 KB f64, XOR-swizzled double2 groups) in
// LDS; thread = (slot, n, h-half) does a private serial f64 FMA loop.
// No per-lane register table (round-2 version spilled at the default
// 64-VGPR cap: FETCH 439MB/WRITE 100MB of scratch traffic; forcing the cap
// up via __launch_bounds__(256,2) aborted in round 3). ~30 VGPRs here.
// ---------------------------------------------------------------------------
__global__ __launch_bounds__(256) void k_hash(const float* __restrict__ x, int rows,
                                              const double* __restrict__ psumT,
                                              unsigned char* __restrict__ outb,
                                              u32* __restrict__ hist16, int do_hist) {
    __shared__ __align__(16) char smem[65536];
    float*  sX    = (float*)smem;                    // [16][512] float, col-group g stored at g^row
    double* sPsum = (double*)(smem + 32768);         // [n][512] dbl, dbl2-group G stored at G^n
    double* sPart = (double*)smem;                   // aliases sX after sync: [slot][n][half]

    const int tid  = threadIdx.x;
    const int n    = tid & 7;
    const int slot = (tid >> 3) & 15;
    const int half = tid >> 7;                       // 0 or 1
    const int lane = tid & 63;

    // load Psum table into LDS (swizzled), once per block
    for (int i = tid; i < HID * NHASH; i += 256) {
        int h = i >> 3, nn = i & 7;
        sPsum[nn * 512 + ((((h >> 1) ^ nn) << 1) | (h & 1))] = psumT[i];
    }

    const double* pn = sPsum + (size_t)n * 512;
    const int h0 = half * 256;
    const int nTiles = rows / ROWS_TILE;

    for (int t = blockIdx.x; t < nTiles; t += gridDim.x) {
        const int rowBase = t * ROWS_TILE;

        // stage 16 rows of x into LDS, coalesced global float4 reads
        for (int i = tid; i < ROWS_TILE * (HID / 4); i += 256) {
            int row = i >> 7, grp = i & 127;
            float4 v = *(const float4*)(x + (size_t)(rowBase + row) * HID + grp * 4);
            *(float4*)(sX + row * HID + ((grp ^ row) << 2)) = v;
        }
        __syncthreads();

        // private dot: acc = sum_h x[slot][h] * psum[h][n] over this half
        double a0 = 0.0, a1 = 0.0, a2 = 0.0, a3 = 0.0;
        const float* sxs = sX + slot * HID;
        #pragma unroll 4
        for (int g2 = 0; g2 < 64; g2++) {
            int h = h0 + g2 * 4;
            float4 xv = *(const float4*)(sxs + (((h >> 2) ^ slot) << 2));
            double2 p0 = *(const double2*)(pn + ((((h >> 1)    ) ^ n) << 1));
            double2 p1 = *(const double2*)(pn + ((((h >> 1) + 1) ^ n) << 1));
            a0 = fma((double)xv.x, p0.x, a0);
            a1 = fma((double)xv.y, p0.y, a1);
            a2 = fma((double)xv.z, p1.x, a2);
            a3 = fma((double)xv.w, p1.y, a3);
        }
        double acc = (a0 + a1) + (a2 + a3);
        __syncthreads();                             // done reading sX

        sPart[slot * 16 + n * 2 + half] = acc;       // aliases sX region (safe post-sync)
        __syncthreads();

        if (half == 0) {
            double tot = acc + sPart[slot * 16 + n * 2 + 1];
            u64 mask = __ballot(tot > 0.0);
            if (n == 0) {
                u32 byte = (u32)((mask >> ((lane >> 3) * 8)) & 0xffull);
                int row = rowBase + slot;
                outb[row] = (unsigned char)byte;
                if (do_hist) atomicAdd(&hist16[(row / SLICE_SZ) * 256 + byte], 1u);
            }
        }
        __syncthreads();                             // protect sPart vs next tile's staging
    }
}

// ---------------------------------------------------------------------------
// K3: prefix sums: bucketCnt, bucketOff (exclusive over buckets),
// off16[s][v] = bucketOff[v] + sum_{s'<s} hist16[s'][v]
// ---------------------------------------------------------------------------
__global__ __launch_bounds__(256) void k_scan(const u32* __restrict__ hist16,
                                              u32* __restrict__ bucketCnt,
                                              u32* __restrict__ bucketOff,
                                              u32* __restrict__ off16) {
    __shared__ u32 sh[256], sh2[256];
    int v = threadIdx.x;
    u32 tot = 0;
    for (int s = 0; s < NSLICE; s++) tot += hist16[s * 256 + v];
    bucketCnt[v] = tot;
    sh[v] = tot;
    __syncthreads();
    if (v == 0) {
        u32 run = 0;
        for (int u = 0; u < 256; u++) { sh2[u] = run; run += sh[u]; }
    }
    __syncthreads();
    u32 base = sh2[v];
    bucketOff[v] = base;
    for (int s = 0; s < NSLICE; s++) { off16[s * 256 + v] = base; base += hist16[s * 256 + v]; }
}

// ---------------------------------------------------------------------------
// K4: stable compaction: bucketList sorted by (hash byte, index ascending).
// block = (bucket_group of 4, slice); wave per bucket; ballot-rank writes.
// ---------------------------------------------------------------------------
__global__ __launch_bounds__(256) void k_compact(const unsigned char* __restrict__ khash,
                                                 const u32* __restrict__ off16,
                                                 u32* __restrict__ bucketList) {
    __shared__ unsigned char sh[SLICE_SZ];
    int s  = blockIdx.x & (NSLICE - 1);
    int bg = blockIdx.x >> 4;
    ((uint4*)sh)[threadIdx.x] = ((const uint4*)(khash + (size_t)s * SLICE_SZ))[threadIdx.x];
    __syncthreads();
    int w = threadIdx.x >> 6, lane = threadIdx.x & 63;
    int v = bg * 4 + w;
    u32 base = off16[s * 256 + v];
    for (int i = 0; i < SLICE_SZ / 64; i++) {
        int c = i * 64 + lane;
        unsigned char byte = sh[c];
        bool hit = (byte == (unsigned char)v);
        u64 m = __ballot(hit);
        if (hit) {
            int rank = __popcll(m & ((1ull << lane) - 1ull));
            bucketList[base + rank] = (u32)(s * SLICE_SZ + c);
        }
        base += (u32)__popcll(m);
    }
}

// ---------------------------------------------------------------------------
// K5: per-query top-32 by (hamming distance, index). Wave per query.
// ---------------------------------------------------------------------------
__global__ __launch_bounds__(256) void k_select(const unsigned char* __restrict__ qhash,
                                                const u32* __restrict__ bucketCnt,
                                                const u32* __restrict__ bucketOff,
                                                const u32* __restrict__ bucketList,
                                                int* __restrict__ topIdx) {
    __shared__ u32 sCnt[256], sOff[256];
    __shared__ int sPos[4];
    int tid = threadIdx.x;
    sCnt[tid] = bucketCnt[tid];
    sOff[tid] = bucketOff[tid];
    int w = tid >> 6, lane = tid & 63;
    if (lane == 0) sPos[w] = 0;
    __syncthreads();

    int q = blockIdx.x * 4 + w;
    u32 qh = qhash[q];

    int d[4]; u32 cnt[4], off[4];
    #pragma unroll
    for (int jj = 0; jj < 4; jj++) {
        int v = lane + jj * 64;
        d[jj] = __popc(qh ^ (u32)v);
        cnt[jj] = sCnt[v];
        off[jj] = sOff[v];
    }

    u32 ct[9];
    #pragma unroll
    for (int t = 0; t < 9; t++) {
        u32 c = 0;
        #pragma unroll
        for (int jj = 0; jj < 4; jj++) c += (d[jj] == t) ? cnt[jj] : 0u;
        #pragma unroll
        for (int s = 32; s >= 1; s >>= 1) c += __shfl_xor(c, s, 64);
        ct[t] = c;
    }

    int dcut = 0; u32 run = 0, before = 0;
    for (int t = 0; t < 9; t++) {
        before = run; run += ct[t];
        if (run >= TOPK) { dcut = t; break; }
    }
    int need = TOPK - (int)before;

    #pragma unroll
    for (int jj = 0; jj < 4; jj++) {
        if (d[jj] < dcut && cnt[jj] > 0) {
            int base = atomicAdd(&sPos[w], (int)cnt[jj]);
            for (u32 e = 0; e < cnt[jj]; e++)
                topIdx[q * TOPK + base + e] = (int)bucketList[off[jj] + e];
        }
    }

    int nb = 0;
    #pragma unroll
    for (int jj = 0; jj < 4; jj++) nb += (d[jj] == dcut) ? 1 : 0;
    #pragma unroll
    for (int s = 32; s >= 1; s >>= 1) nb += __shfl_xor(nb, s, 64);

    if (nb == 1) {
        u32 boff = 0xFFFFFFFFu;
        #pragma unroll
        for (int jj = 0; jj < 4; jj++) if (d[jj] == dcut) boff = off[jj];
        #pragma unroll
        for (int s = 32; s >= 1; s >>= 1) boff = min(boff, __shfl_xor(boff, s, 64));
        if (lane < need)
            topIdx[q * TOPK + (int)before + lane] = (int)bucketList[boff + lane];
    } else {
        u32 pos[4], end[4]; int val[4];
        #pragma unroll
        for (int jj = 0; jj < 4; jj++) {
            if (d[jj] == dcut && cnt[jj] > 0) {
                pos[jj] = off[jj]; end[jj] = off[jj] + cnt[jj];
                val[jj] = (int)bucketList[pos[jj]];
            } else { pos[jj] = 0; end[jj] = 0; val[jj] = 0x7fffffff; }
        }
        for (int it = 0; it < need; it++) {
            int m = min(min(val[0], val[1]), min(val[2], val[3]));
            int g = m;
            #pragma unroll
            for (int s = 32; s >= 1; s >>= 1) g = min(g, __shfl_xor(g, s, 64));
            if (lane == 0) topIdx[q * TOPK + (int)before + it] = g;
            if (m == g && g != 0x7fffffff) {
                #pragma unroll
                for (int jj = 0; jj < 4; jj++) {
                    if (val[jj] == g) {
                        pos[jj]++;
                        val[jj] = (pos[jj] < end[jj]) ? (int)bucketList[pos[jj]] : 0x7fffffff;
                        break;
                    }
                }
            }
        }
    }
}

// ---------------------------------------------------------------------------
// K6: gather + scores + softmax + weighted V sum. Block per query.
// ---------------------------------------------------------------------------
__global__ __launch_bounds__(256) void k_attn(const float* __restrict__ keys,
                                              const float* __restrict__ vals,
                                              const float* __restrict__ query,
                                              const int* __restrict__ topIdx,
                                              float* __restrict__ mo) {
    __shared__ int sIdx[TOPK];
    __shared__ float sSc[TOPK], sE[TOPK];
    int b = blockIdx.x, tid = threadIdx.x;
    if (tid < TOPK) sIdx[tid] = topIdx[b * TOPK + tid];
    __syncthreads();

    int w = tid >> 6, lane = tid & 63;
    const float4* qp = (const float4*)(query + (size_t)b * HID + lane * 8);
    float4 qa = qp[0], qb = qp[1];

    for (int i = w * 8; i < w * 8 + 8; i++) {
        int idx = sIdx[i];
        const float4* kp = (const float4*)(keys + (size_t)idx * HID + lane * 8);
        float4 ka = kp[0], kb = kp[1];
        float dot = qa.x * ka.x + qa.y * ka.y + qa.z * ka.z + qa.w * ka.w
                  + qb.x * kb.x + qb.y * kb.y + qb.z * kb.z + qb.w * kb.w;
        #pragma unroll
        for (int s = 32; s >= 1; s >>= 1) dot += __shfl_xor(dot, s, 64);
        if (lane == 0) sSc[i] = dot * 0.04419417382415922f;  // 1/sqrt(512)
    }
    __syncthreads();

    if (tid < TOPK) {
        float m = -1e30f;
        for (int i = 0; i < TOPK; i++) m = fmaxf(m, sSc[i]);
        sE[tid] = expf(sSc[tid] - m);
    }
    __syncthreads();

    float sum = 0.f;
    for (int i = 0; i < TOPK; i++) sum += sE[i];
    float inv = 1.0f / sum;

    int h0 = tid, h1 = tid + 256;
    float a0 = 0.f, a1 = 0.f;
    for (int i = 0; i < TOPK; i++) {
        int idx = sIdx[i];
        float e = sE[i];
        a0 += e * vals[(size_t)idx * HID + h0];
        a1 += e * vals[(size_t)idx * HID + h1];
    }
    mo[(size_t)b * HID + h0] = a0 * inv;
    mo[(size_t)b * HID + h1] = a1 * inv;
}

// ---------------------------------------------------------------------------
// K7: transpose out_w [o][h] -> wt [h][o] for coalesced projection reads
// ---------------------------------------------------------------------------
__global__ __launch_bounds__(256) void k_transpose(const float* __restrict__ w,
                                                   float* __restrict__ wt) {
    __shared__ float tile[64][65];
    int bx = blockIdx.x, by = blockIdx.y;
    int tx = threadIdx.x & 63, ty = threadIdx.x >> 6;
    for (int r = ty; r < 64; r += 4)
        tile[r][tx] = w[(size_t)(by * 64 + r) * HID + bx * 64 + tx];
    __syncthreads();
    for (int r = ty; r < 64; r += 4)
        wt[(size_t)(bx * 64 + r) * HID + by * 64 + tx] = tile[tx][r];
}

// ---------------------------------------------------------------------------
// K8: out[b][o] = sum_h mo[b][h] * wt[h][o] + bias[o]; 8 b-rows per block.
// ---------------------------------------------------------------------------
__global__ __launch_bounds__(256) void k_proj(const float* __restrict__ mo,
                                              const float* __restrict__ wt,
                                              const float* __restrict__ bias,
                                              float* __restrict__ out) {
    int tid = threadIdx.x;
    int o = (blockIdx.x & 1) * 256 + tid;
    int bb = (blockIdx.x >> 1) * 8;
    float acc[8];
    #pragma unroll
    for (int r = 0; r < 8; r++) acc[r] = 0.f;
    for (int h = 0; h < HID; h++) {
        float wv = wt[(size_t)h * HID + o];
        #pragma unroll
        for (int r = 0; r < 8; r++)
            acc[r] += mo[(size_t)(bb + r) * HID + h] * wv;
    }
    float bv = bias[o];
    #pragma unroll
    for (int r = 0; r < 8; r++)
        out[(size_t)(bb + r) * HID + o] = acc[r] + bv;
}

// ---------------------------------------------------------------------------
extern "C" void kernel_launch(void* const* d_in, const int* in_sizes, int n_in,
                              void* d_out, int out_size, void* d_ws, size_t ws_size,
                              hipStream_t stream) {
    const float* query = (const float*)d_in[0];
    const float* keys  = (const float*)d_in[1];
    const float* vals  = (const float*)d_in[2];
    const float* proj  = (const float*)d_in[3];
    const float* outw  = (const float*)d_in[4];
    const float* outb  = (const float*)d_in[5];
    float* out = (float*)d_out;

    char* ws = (char*)d_ws;
    double*        psumT      = (double*)(ws + 0);              // 32 KB
    unsigned char* qhash      = (unsigned char*)(ws + 32768);   // 2 KB
    unsigned char* khash      = (unsigned char*)(ws + 34816);   // 64 KB
    u32*           hist16     = (u32*)(ws + 100352);            // 16 KB
    u32*           bucketCnt  = (u32*)(ws + 116736);            // 1 KB
    u32*           bucketOff  = (u32*)(ws + 117760);            // 1 KB
    u32*           off16      = (u32*)(ws + 118784);            // 16 KB
    u32*           bucketList = (u32*)(ws + 135168);            // 256 KB
    int*           topIdx     = (int*)(ws + 397312);            // 256 KB
    float*         mo         = (float*)(ws + 659456);          // 4 MB
    float*         wt         = (float*)(ws + 4853760);         // 1 MB
    (void)in_sizes; (void)n_in; (void)out_size; (void)ws_size;

    hipMemsetAsync(hist16, 0, 16384, stream);
    k_psum<<<2, 256, 0, stream>>>(proj, psumT);
    k_hash<<<128, 256, 0, stream>>>(query, BATCH, psumT, qhash, hist16, 0);
    k_hash<<<512, 256, 0, stream>>>(keys, CAP, psumT, khash, hist16, 1);
    k_scan<<<1, 256, 0, stream>>>(hist16, bucketCnt, bucketOff, off16);
    k_compact<<<1024, 256, 0, stream>>>(khash, off16, bucketList);
    k_select<<<BATCH / 4, 256, 0, stream>>>(qhash, bucketCnt, bucketOff, bucketList, topIdx);
    k_attn<<<BATCH, 256, 0, stream>>>(keys, vals, query, topIdx, mo);
    k_transpose<<<dim3(8, 8), 256, 0, stream>>>(outw, wt);
    k_proj<<<512, 256, 0, stream>>>(mo, wt, outb, out);
}

// Round 5
// 391.104 us; speedup vs baseline: 1.3196x; 1.0034x over previous
//
#include <hip/hip_runtime.h>
#include <stdint.h>

#define BATCH  2048
#define HID    512
#define CAP    65536
#define NHASH  8
#define TOPK   32
#define NSLICE 16
#define SLICE_SZ (CAP / NSLICE)   // 4096
#define ROWS_TILE 16

typedef unsigned int   u32;
typedef unsigned long long u64;

__device__ __forceinline__ double dshfl_xor(double v, int m) {
    int2 a = __builtin_bit_cast(int2, v);
    a.x = __shfl_xor(a.x, m, 64);
    a.y = __shfl_xor(a.y, m, 64);
    return __builtin_bit_cast(double, a);
}

// ---------------------------------------------------------------------------
// K1: Psum[h][n] = sum_d P[n][h][d] in f64, stored f64 [h][n]
// ---------------------------------------------------------------------------
__global__ __launch_bounds__(256) void k_psum(const float* __restrict__ proj,
                                              double* __restrict__ psumT) {
    int h = blockIdx.x * blockDim.x + threadIdx.x;
    if (h >= HID) return;
    for (int n = 0; n < NHASH; n++) {
        const float* p = proj + ((size_t)n * HID + h) * 16;
        double s = 0.0;
        #pragma unroll
        for (int d = 0; d < 16; d++) s += (double)p[d];
        psumT[(size_t)h * NHASH + n] = s;
    }
}

// ---------------------------------------------------------------------------
// K2: hash bytes. Register-held Psum slice per thread (16 f64 = 32 VGPRs,
// loaded once), x staged in LDS (32 KB, XOR-swizzled float4: P = G^((G>>3)&7)
// -> conflict-free reads), f64 FMA + 5-step f64 butterfly over the 32
// column-slice lanes. Round-4 version re-read the Psum table from LDS for
// every row (512 KB/tile, LDS-BW bound at 80 us); this reads only x.
// ---------------------------------------------------------------------------
__global__ void k_hash(const float* __restrict__ x, int rows,
                       const double* __restrict__ psumT,
                       unsigned char* __restrict__ outb,
                       u32* __restrict__ hist16, int do_hist) {
    __shared__ __align__(16) float4 sX[ROWS_TILE * 128];   // 32 KB, swizzled
    __shared__ u32 sBits[ROWS_TILE];

    const int tid = threadIdx.x;
    const int n   = tid >> 5;          // hash bit 0..7
    const int g   = tid & 31;          // column-slice 0..31
    const int w   = tid >> 6;          // wave id (n = 2w, 2w+1 inside)
    const int lane = tid & 63;

    // Psum slice into registers, once: psumR[j][jj] = Psum[h(j,jj)][n],
    // h = j*128 + g*4 + jj (matches the swizzled x-read below).
    double psumR[4][4];
    #pragma unroll
    for (int j = 0; j < 4; j++)
        #pragma unroll
        for (int jj = 0; jj < 4; jj++)
            psumR[j][jj] = psumT[(size_t)(j * 128 + g * 4 + jj) * NHASH + n];

    const int nTiles = rows / ROWS_TILE;
    for (int t = blockIdx.x; t < nTiles; t += gridDim.x) {
        const int rowBase = t * ROWS_TILE;

        if (tid < ROWS_TILE) sBits[tid] = 0u;
        // stage 16 rows, coalesced global float4; store group G at G^((G>>3)&7)
        for (int i = tid; i < ROWS_TILE * 128; i += 256) {
            int row = i >> 7, G = i & 127;
            float4 v = ((const float4*)(x + (size_t)(rowBase + row) * HID))[G];
            sX[row * 128 + (G ^ ((G >> 3) & 7))] = v;
        }
        __syncthreads();

        for (int r = 0; r < ROWS_TILE; r++) {
            double acc = 0.0;
            #pragma unroll
            for (int j = 0; j < 4; j++) {
                int G = j * 32 + g;
                float4 xv = sX[r * 128 + (G ^ ((G >> 3) & 7))];
                acc = fma((double)xv.x, psumR[j][0], acc);
                acc = fma((double)xv.y, psumR[j][1], acc);
                acc = fma((double)xv.z, psumR[j][2], acc);
                acc = fma((double)xv.w, psumR[j][3], acc);
            }
            #pragma unroll
            for (int m = 16; m >= 1; m >>= 1) acc += dshfl_xor(acc, m);
            // all 32 g-lanes of each n-half now hold sum(r, n)
            u64 bm = __ballot(acc > 0.0);
            if (lane == 0) {
                u32 bits = ((u32)(bm & 1ull) << (2 * w)) |
                           ((u32)((bm >> 32) & 1ull) << (2 * w + 1));
                atomicOr(&sBits[r], bits);
            }
        }
        __syncthreads();

        if (tid < ROWS_TILE) {
            int row = rowBase + tid;
            u32 byte = sBits[tid];
            outb[row] = (unsigned char)byte;
            if (do_hist) atomicAdd(&hist16[(row / SLICE_SZ) * 256 + byte], 1u);
        }
        __syncthreads();   // protect sBits/sX vs next tile
    }
}

// ---------------------------------------------------------------------------
// K3: prefix sums: bucketCnt, bucketOff (exclusive over buckets),
// off16[s][v] = bucketOff[v] + sum_{s'<s} hist16[s'][v]
// ---------------------------------------------------------------------------
__global__ __launch_bounds__(256) void k_scan(const u32* __restrict__ hist16,
                                              u32* __restrict__ bucketCnt,
                                              u32* __restrict__ bucketOff,
                                              u32* __restrict__ off16) {
    __shared__ u32 sh[256], sh2[256];
    int v = threadIdx.x;
    u32 tot = 0;
    for (int s = 0; s < NSLICE; s++) tot += hist16[s * 256 + v];
    bucketCnt[v] = tot;
    sh[v] = tot;
    __syncthreads();
    if (v == 0) {
        u32 run = 0;
        for (int u = 0; u < 256; u++) { sh2[u] = run; run += sh[u]; }
    }
    __syncthreads();
    u32 base = sh2[v];
    bucketOff[v] = base;
    for (int s = 0; s < NSLICE; s++) { off16[s * 256 + v] = base; base += hist16[s * 256 + v]; }
}

// ---------------------------------------------------------------------------
// K4: stable compaction: bucketList sorted by (hash byte, index ascending).
// ---------------------------------------------------------------------------
__global__ __launch_bounds__(256) void k_compact(const unsigned char* __restrict__ khash,
                                                 const u32* __restrict__ off16,
                                                 u32* __restrict__ bucketList) {
    __shared__ unsigned char sh[SLICE_SZ];
    int s  = blockIdx.x & (NSLICE - 1);
    int bg = blockIdx.x >> 4;
    ((uint4*)sh)[threadIdx.x] = ((const uint4*)(khash + (size_t)s * SLICE_SZ))[threadIdx.x];
    __syncthreads();
    int w = threadIdx.x >> 6, lane = threadIdx.x & 63;
    int v = bg * 4 + w;
    u32 base = off16[s * 256 + v];
    for (int i = 0; i < SLICE_SZ / 64; i++) {
        int c = i * 64 + lane;
        unsigned char byte = sh[c];
        bool hit = (byte == (unsigned char)v);
        u64 m = __ballot(hit);
        if (hit) {
            int rank = __popcll(m & ((1ull << lane) - 1ull));
            bucketList[base + rank] = (u32)(s * SLICE_SZ + c);
        }
        base += (u32)__popcll(m);
    }
}

// ---------------------------------------------------------------------------
// K5: per-query top-32 by (hamming distance, index). Wave per query.
// ---------------------------------------------------------------------------
__global__ __launch_bounds__(256) void k_select(const unsigned char* __restrict__ qhash,
                                                const u32* __restrict__ bucketCnt,
                                                const u32* __restrict__ bucketOff,
                                                const u32* __restrict__ bucketList,
                                                int* __restrict__ topIdx) {
    __shared__ u32 sCnt[256], sOff[256];
    __shared__ int sPos[4];
    int tid = threadIdx.x;
    sCnt[tid] = bucketCnt[tid];
    sOff[tid] = bucketOff[tid];
    int w = tid >> 6, lane = tid & 63;
    if (lane == 0) sPos[w] = 0;
    __syncthreads();

    int q = blockIdx.x * 4 + w;
    u32 qh = qhash[q];

    int d[4]; u32 cnt[4], off[4];
    #pragma unroll
    for (int jj = 0; jj < 4; jj++) {
        int v = lane + jj * 64;
        d[jj] = __popc(qh ^ (u32)v);
        cnt[jj] = sCnt[v];
        off[jj] = sOff[v];
    }

    u32 ct[9];
    #pragma unroll
    for (int t = 0; t < 9; t++) {
        u32 c = 0;
        #pragma unroll
        for (int jj = 0; jj < 4; jj++) c += (d[jj] == t) ? cnt[jj] : 0u;
        #pragma unroll
        for (int s = 32; s >= 1; s >>= 1) c += __shfl_xor(c, s, 64);
        ct[t] = c;
    }

    int dcut = 0; u32 run = 0, before = 0;
    for (int t = 0; t < 9; t++) {
        before = run; run += ct[t];
        if (run >= TOPK) { dcut = t; break; }
    }
    int need = TOPK - (int)before;

    #pragma unroll
    for (int jj = 0; jj < 4; jj++) {
        if (d[jj] < dcut && cnt[jj] > 0) {
            int base = atomicAdd(&sPos[w], (int)cnt[jj]);
            for (u32 e = 0; e < cnt[jj]; e++)
                topIdx[q * TOPK + base + e] = (int)bucketList[off[jj] + e];
        }
    }

    int nb = 0;
    #pragma unroll
    for (int jj = 0; jj < 4; jj++) nb += (d[jj] == dcut) ? 1 : 0;
    #pragma unroll
    for (int s = 32; s >= 1; s >>= 1) nb += __shfl_xor(nb, s, 64);

    if (nb == 1) {
        u32 boff = 0xFFFFFFFFu;
        #pragma unroll
        for (int jj = 0; jj < 4; jj++) if (d[jj] == dcut) boff = off[jj];
        #pragma unroll
        for (int s = 32; s >= 1; s >>= 1) boff = min(boff, __shfl_xor(boff, s, 64));
        if (lane < need)
            topIdx[q * TOPK + (int)before + lane] = (int)bucketList[boff + lane];
    } else {
        u32 pos[4], end[4]; int val[4];
        #pragma unroll
        for (int jj = 0; jj < 4; jj++) {
            if (d[jj] == dcut && cnt[jj] > 0) {
                pos[jj] = off[jj]; end[jj] = off[jj] + cnt[jj];
                val[jj] = (int)bucketList[pos[jj]];
            } else { pos[jj] = 0; end[jj] = 0; val[jj] = 0x7fffffff; }
        }
        for (int it = 0; it < need; it++) {
            int m = min(min(val[0], val[1]), min(val[2], val[3]));
            int g = m;
            #pragma unroll
            for (int s = 32; s >= 1; s >>= 1) g = min(g, __shfl_xor(g, s, 64));
            if (lane == 0) topIdx[q * TOPK + (int)before + it] = g;
            if (m == g && g != 0x7fffffff) {
                #pragma unroll
                for (int jj = 0; jj < 4; jj++) {
                    if (val[jj] == g) {
                        pos[jj]++;
                        val[jj] = (pos[jj] < end[jj]) ? (int)bucketList[pos[jj]] : 0x7fffffff;
                        break;
                    }
                }
            }
        }
    }
}

// ---------------------------------------------------------------------------
// K6: gather + scores + softmax + weighted V sum. Block per query.
// ---------------------------------------------------------------------------
__global__ __launch_bounds__(256) void k_attn(const float* __restrict__ keys,
                                              const float* __restrict__ vals,
                                              const float* __restrict__ query,
                                              const int* __restrict__ topIdx,
                                              float* __restrict__ mo) {
    __shared__ int sIdx[TOPK];
    __shared__ float sSc[TOPK], sE[TOPK];
    int b = blockIdx.x, tid = threadIdx.x;
    if (tid < TOPK) sIdx[tid] = topIdx[b * TOPK + tid];
    __syncthreads();

    int w = tid >> 6, lane = tid & 63;
    const float4* qp = (const float4*)(query + (size_t)b * HID + lane * 8);
    float4 qa = qp[0], qb = qp[1];

    for (int i = w * 8; i < w * 8 + 8; i++) {
        int idx = sIdx[i];
        const float4* kp = (const float4*)(keys + (size_t)idx * HID + lane * 8);
        float4 ka = kp[0], kb = kp[1];
        float dot = qa.x * ka.x + qa.y * ka.y + qa.z * ka.z + qa.w * ka.w
                  + qb.x * kb.x + qb.y * kb.y + qb.z * kb.z + qb.w * kb.w;
        #pragma unroll
        for (int s = 32; s >= 1; s >>= 1) dot += __shfl_xor(dot, s, 64);
        if (lane == 0) sSc[i] = dot * 0.04419417382415922f;  // 1/sqrt(512)
    }
    __syncthreads();

    if (tid < TOPK) {
        float m = -1e30f;
        for (int i = 0; i < TOPK; i++) m = fmaxf(m, sSc[i]);
        sE[tid] = expf(sSc[tid] - m);
    }
    __syncthreads();

    float sum = 0.f;
    for (int i = 0; i < TOPK; i++) sum += sE[i];
    float inv = 1.0f / sum;

    int h0 = tid, h1 = tid + 256;
    float a0 = 0.f, a1 = 0.f;
    for (int i = 0; i < TOPK; i++) {
        int idx = sIdx[i];
        float e = sE[i];
        a0 += e * vals[(size_t)idx * HID + h0];
        a1 += e * vals[(size_t)idx * HID + h1];
    }
    mo[(size_t)b * HID + h0] = a0 * inv;
    mo[(size_t)b * HID + h1] = a1 * inv;
}

// ---------------------------------------------------------------------------
// K7: transpose out_w [o][h] -> wt [h][o] for coalesced projection reads
// ---------------------------------------------------------------------------
__global__ __launch_bounds__(256) void k_transpose(const float* __restrict__ w,
                                                   float* __restrict__ wt) {
    __shared__ float tile[64][65];
    int bx = blockIdx.x, by = blockIdx.y;
    int tx = threadIdx.x & 63, ty = threadIdx.x >> 6;
    for (int r = ty; r < 64; r += 4)
        tile[r][tx] = w[(size_t)(by * 64 + r) * HID + bx * 64 + tx];
    __syncthreads();
    for (int r = ty; r < 64; r += 4)
        wt[(size_t)(bx * 64 + r) * HID + by * 64 + tx] = tile[tx][r];
}

// ---------------------------------------------------------------------------
// K8: out[b][o] = sum_h mo[b][h] * wt[h][o] + bias[o]; 8 b-rows per block.
// ---------------------------------------------------------------------------
__global__ __launch_bounds__(256) void k_proj(const float* __restrict__ mo,
                                              const float* __restrict__ wt,
                                              const float* __restrict__ bias,
                                              float* __restrict__ out) {
    int tid = threadIdx.x;
    int o = (blockIdx.x & 1) * 256 + tid;
    int bb = (blockIdx.x >> 1) * 8;
    float acc[8];
    #pragma unroll
    for (int r = 0; r < 8; r++) acc[r] = 0.f;
    for (int h = 0; h < HID; h++) {
        float wv = wt[(size_t)h * HID + o];
        #pragma unroll
        for (int r = 0; r < 8; r++)
            acc[r] += mo[(size_t)(bb + r) * HID + h] * wv;
    }
    float bv = bias[o];
    #pragma unroll
    for (int r = 0; r < 8; r++)
        out[(size_t)(bb + r) * HID + o] = acc[r] + bv;
}

// ---------------------------------------------------------------------------
extern "C" void kernel_launch(void* const* d_in, const int* in_sizes, int n_in,
                              void* d_out, int out_size, void* d_ws, size_t ws_size,
                              hipStream_t stream) {
    const float* query = (const float*)d_in[0];
    const float* keys  = (const float*)d_in[1];
    const float* vals  = (const float*)d_in[2];
    const float* proj  = (const float*)d_in[3];
    const float* outw  = (const float*)d_in[4];
    const float* outb  = (const float*)d_in[5];
    float* out = (float*)d_out;

    char* ws = (char*)d_ws;
    double*        psumT      = (double*)(ws + 0);              // 32 KB
    unsigned char* qhash      = (unsigned char*)(ws + 32768);   // 2 KB
    unsigned char* khash      = (unsigned char*)(ws + 34816);   // 64 KB
    u32*           hist16     = (u32*)(ws + 100352);            // 16 KB
    u32*           bucketCnt  = (u32*)(ws + 116736);            // 1 KB
    u32*           bucketOff  = (u32*)(ws + 117760);            // 1 KB
    u32*           off16      = (u32*)(ws + 118784);            // 16 KB
    u32*           bucketList = (u32*)(ws + 135168);            // 256 KB
    int*           topIdx     = (int*)(ws + 397312);            // 256 KB
    float*         mo         = (float*)(ws + 659456);          // 4 MB
    float*         wt         = (float*)(ws + 4853760);         // 1 MB
    (void)in_sizes; (void)n_in; (void)out_size; (void)ws_size;

    hipMemsetAsync(hist16, 0, 16384, stream);
    k_psum<<<2, 256, 0, stream>>>(proj, psumT);
    k_hash<<<128, 256, 0, stream>>>(query, BATCH, psumT, qhash, hist16, 0);
    k_hash<<<1024, 256, 0, stream>>>(keys, CAP, psumT, khash, hist16, 1);
    k_scan<<<1, 256, 0, stream>>>(hist16, bucketCnt, bucketOff, off16);
    k_compact<<<1024, 256, 0, stream>>>(khash, off16, bucketList);
    k_select<<<BATCH / 4, 256, 0, stream>>>(qhash, bucketCnt, bucketOff, bucketList, topIdx);
    k_attn<<<BATCH, 256, 0, stream>>>(keys, vals, query, topIdx, mo);
    k_transpose<<<dim3(8, 8), 256, 0, stream>>>(outw, wt);
    k_proj<<<512, 256, 0, stream>>>(mo, wt, outb, out);
}

// Round 7
// 384.922 us; speedup vs baseline: 1.3408x; 1.0161x over previous
//
#include <hip/hip_runtime.h>
#include <stdint.h>

#define BATCH  2048
#define HID    512
#define CAP    65536
#define NHASH  8
#define TOPK   32
#define NSLICE 16
#define SLICE_SZ (CAP / NSLICE)   // 4096
#define ROWS_TILE 16

typedef unsigned int   u32;
typedef unsigned long long u64;
typedef double d4 __attribute__((ext_vector_type(4)));

// ---------------------------------------------------------------------------
// K1: Psum[h][n] = sum_d P[n][h][d] in f64, stored f64 [h][n]
// ---------------------------------------------------------------------------
__global__ __launch_bounds__(256) void k_psum(const float* __restrict__ proj,
                                              double* __restrict__ psumT) {
    int h = blockIdx.x * blockDim.x + threadIdx.x;
    if (h >= HID) return;
    for (int n = 0; n < NHASH; n++) {
        const float* p = proj + ((size_t)n * HID + h) * 16;
        double s = 0.0;
        #pragma unroll
        for (int d = 0; d < 16; d++) s += (double)p[d];
        psumT[(size_t)h * NHASH + n] = s;
    }
}

// ---------------------------------------------------------------------------
// K2: hash bytes via f64 MFMA with RUNTIME SELF-CALIBRATION of the fragment
// layout. Round 6 assumed the standard CDNA C/D map (row=4*(l>>4)+i) for
// v_mfma_f64_16x16x4_f64 and failed correctness; the f64 accumulator layout
// is evidently not the f32-shape one. Three probe MFMAs decode, exactly:
//   - row label per (lane,reg):  A=(l&15)+1, B=1     -> D = 4*(row+1)
//   - col label per (lane,reg):  A=1, B=(l&15)+1     -> D = 4*(col+1)
//   - A/B k-slot pairing:        A=2^(l>>4), B=2^(4*(l>>4)) -> bits k+4k'
// Main loop: x-tile in swizzled LDS, Psum B-fragments in registers (pairing-
// corrected), 32 chained MFMAs per wave (k-range 128w..128w+127), partials
// scattered to sAcc4[w][row][col] by the PROBED map, summed by 16 threads.
// ---------------------------------------------------------------------------
__global__ __launch_bounds__(256, 3) void k_hash(const float* __restrict__ x, int rows,
                                                 const double* __restrict__ psumT,
                                                 unsigned char* __restrict__ outb,
                                                 u32* __restrict__ hist16, int do_hist) {
    __shared__ __align__(16) float sX[ROWS_TILE * HID];     // 32 KB, swizzled
    __shared__ double sAcc4[4][ROWS_TILE][8];               // 4 KB

    const int tid  = threadIdx.x;
    const int w    = tid >> 6;          // wave id -> k range [128w, 128w+128)
    const int m    = (tid & 63) & 15;   // A row / B col label
    const int kk   = (tid & 63) >> 4;   // A/B k-slot label 0..3

    // --- self-calibration probes ---
    d4 z = {0.0, 0.0, 0.0, 0.0};
    d4 pr = __builtin_amdgcn_mfma_f64_16x16x4f64((double)(m + 1), 1.0, z, 0, 0, 0);
    d4 pc = __builtin_amdgcn_mfma_f64_16x16x4f64(1.0, (double)(m + 1), z, 0, 0, 0);
    d4 pp = __builtin_amdgcn_mfma_f64_16x16x4f64((double)(1 << kk),
                                                 (double)(1 << (4 * kk)), z, 0, 0, 0);
    int rowOf[4], colOf[4];
    #pragma unroll
    for (int i = 0; i < 4; i++) {
        rowOf[i] = (int)(pr[i] * 0.25) - 1;
        colOf[i] = (int)(pc[i] * 0.25) - 1;
    }
    u32 pb = (u32)pp[0];                 // 4 set bits: e = kA + 4*kB
    u32 pairPacked = 0;                  // pairA[kB] in bits [2kB, 2kB+1]
    #pragma unroll
    for (int e = 0; e < 16; e++)
        if ((pb >> e) & 1u) pairPacked |= (u32)(e & 3) << (2 * (e >> 2));

    // B fragments, once: B-slot kk holds Psum[128w + 4j + pairA[kk]][n=m]
    const int kAdj = (int)((pairPacked >> (2 * kk)) & 3u);
    double bfrag[32];
    #pragma unroll
    for (int j = 0; j < 32; j++) {
        int kp = 128 * w + 4 * j + kAdj;
        bfrag[j] = (m < 8) ? psumT[(size_t)kp * NHASH + m] : 0.0;
    }

    const int sw = (m & 7) << 2;        // read-side swizzle for row m
    const int nTiles = rows / ROWS_TILE;

    for (int t = blockIdx.x; t < nTiles; t += gridDim.x) {
        const int rowBase = t * ROWS_TILE;

        // stage 16 rows; float4 group G of row r stored at G ^ (r&7)
        for (int i = tid; i < ROWS_TILE * 128; i += 256) {
            int r = i >> 7, G = i & 127;
            float4 v = ((const float4*)(x + (size_t)(rowBase + r) * HID))[G];
            ((float4*)sX)[r * 128 + (G ^ (r & 7))] = v;
        }
        __syncthreads();

        d4 acc = {0.0, 0.0, 0.0, 0.0};
        const float* sxm = sX + m * HID;
        #pragma unroll
        for (int j = 0; j < 32; j++) {
            int k = 128 * w + 4 * j + kk;
            double a = (double)sxm[k ^ sw];
            acc = __builtin_amdgcn_mfma_f64_16x16x4f64(a, bfrag[j], acc, 0, 0, 0);
        }
        // scatter partials by the PROBED (row,col); each wave covers every
        // (row, col<8) exactly once, so sAcc4 is fully overwritten per tile.
        #pragma unroll
        for (int i = 0; i < 4; i++) {
            if (((unsigned)rowOf[i] < (unsigned)ROWS_TILE) && ((unsigned)colOf[i] < 8u))
                sAcc4[w][rowOf[i]][colOf[i]] = acc[i];
        }
        __syncthreads();

        if (tid < ROWS_TILE) {
            u32 byte = 0;
            #pragma unroll
            for (int n = 0; n < 8; n++) {
                double s = sAcc4[0][tid][n] + sAcc4[1][tid][n]
                         + sAcc4[2][tid][n] + sAcc4[3][tid][n];
                if (s > 0.0) byte |= (1u << n);
            }
            outb[rowBase + tid] = (unsigned char)byte;
            if (do_hist) atomicAdd(&hist16[((rowBase + tid) / SLICE_SZ) * 256 + byte], 1u);
        }
        // no barrier needed here: next-tile sAcc4 writes happen after the
        // next __syncthreads(); readers finish before reaching it.
    }
}

// ---------------------------------------------------------------------------
// K3: prefix sums: bucketCnt, bucketOff (exclusive over buckets),
// off16[s][v] = bucketOff[v] + sum_{s'<s} hist16[s'][v]
// ---------------------------------------------------------------------------
__global__ __launch_bounds__(256) void k_scan(const u32* __restrict__ hist16,
                                              u32* __restrict__ bucketCnt,
                                              u32* __restrict__ bucketOff,
                                              u32* __restrict__ off16) {
    __shared__ u32 sh[256], sh2[256];
    int v = threadIdx.x;
    u32 tot = 0;
    for (int s = 0; s < NSLICE; s++) tot += hist16[s * 256 + v];
    bucketCnt[v] = tot;
    sh[v] = tot;
    __syncthreads();
    if (v == 0) {
        u32 run = 0;
        for (int u = 0; u < 256; u++) { sh2[u] = run; run += sh[u]; }
    }
    __syncthreads();
    u32 base = sh2[v];
    bucketOff[v] = base;
    for (int s = 0; s < NSLICE; s++) { off16[s * 256 + v] = base; base += hist16[s * 256 + v]; }
}

// ---------------------------------------------------------------------------
// K4: stable compaction: bucketList sorted by (hash byte, index ascending).
// ---------------------------------------------------------------------------
__global__ __launch_bounds__(256) void k_compact(const unsigned char* __restrict__ khash,
                                                 const u32* __restrict__ off16,
                                                 u32* __restrict__ bucketList) {
    __shared__ unsigned char sh[SLICE_SZ];
    int s  = blockIdx.x & (NSLICE - 1);
    int bg = blockIdx.x >> 4;
    ((uint4*)sh)[threadIdx.x] = ((const uint4*)(khash + (size_t)s * SLICE_SZ))[threadIdx.x];
    __syncthreads();
    int w = threadIdx.x >> 6, lane = threadIdx.x & 63;
    int v = bg * 4 + w;
    u32 base = off16[s * 256 + v];
    for (int i = 0; i < SLICE_SZ / 64; i++) {
        int c = i * 64 + lane;
        unsigned char byte = sh[c];
        bool hit = (byte == (unsigned char)v);
        u64 m = __ballot(hit);
        if (hit) {
            int rank = __popcll(m & ((1ull << lane) - 1ull));
            bucketList[base + rank] = (u32)(s * SLICE_SZ + c);
        }
        base += (u32)__popcll(m);
    }
}

// ---------------------------------------------------------------------------
// K5: per-query top-32 by (hamming distance, index). Wave per query.
// ---------------------------------------------------------------------------
__global__ __launch_bounds__(256) void k_select(const unsigned char* __restrict__ qhash,
                                                const u32* __restrict__ bucketCnt,
                                                const u32* __restrict__ bucketOff,
                                                const u32* __restrict__ bucketList,
                                                int* __restrict__ topIdx) {
    __shared__ u32 sCnt[256], sOff[256];
    __shared__ int sPos[4];
    int tid = threadIdx.x;
    sCnt[tid] = bucketCnt[tid];
    sOff[tid] = bucketOff[tid];
    int w = tid >> 6, lane = tid & 63;
    if (lane == 0) sPos[w] = 0;
    __syncthreads();

    int q = blockIdx.x * 4 + w;
    u32 qh = qhash[q];

    int d[4]; u32 cnt[4], off[4];
    #pragma unroll
    for (int jj = 0; jj < 4; jj++) {
        int v = lane + jj * 64;
        d[jj] = __popc(qh ^ (u32)v);
        cnt[jj] = sCnt[v];
        off[jj] = sOff[v];
    }

    u32 ct[9];
    #pragma unroll
    for (int t = 0; t < 9; t++) {
        u32 c = 0;
        #pragma unroll
        for (int jj = 0; jj < 4; jj++) c += (d[jj] == t) ? cnt[jj] : 0u;
        #pragma unroll
        for (int s = 32; s >= 1; s >>= 1) c += __shfl_xor(c, s, 64);
        ct[t] = c;
    }

    int dcut = 0; u32 run = 0, before = 0;
    for (int t = 0; t < 9; t++) {
        before = run; run += ct[t];
        if (run >= TOPK) { dcut = t; break; }
    }
    int need = TOPK - (int)before;

    #pragma unroll
    for (int jj = 0; jj < 4; jj++) {
        if (d[jj] < dcut && cnt[jj] > 0) {
            int base = atomicAdd(&sPos[w], (int)cnt[jj]);
            for (u32 e = 0; e < cnt[jj]; e++)
                topIdx[q * TOPK + base + e] = (int)bucketList[off[jj] + e];
        }
    }

    int nb = 0;
    #pragma unroll
    for (int jj = 0; jj < 4; jj++) nb += (d[jj] == dcut) ? 1 : 0;
    #pragma unroll
    for (int s = 32; s >= 1; s >>= 1) nb += __shfl_xor(nb, s, 64);

    if (nb == 1) {
        u32 boff = 0xFFFFFFFFu;
        #pragma unroll
        for (int jj = 0; jj < 4; jj++) if (d[jj] == dcut) boff = off[jj];
        #pragma unroll
        for (int s = 32; s >= 1; s >>= 1) boff = min(boff, __shfl_xor(boff, s, 64));
        if (lane < need)
            topIdx[q * TOPK + (int)before + lane] = (int)bucketList[boff + lane];
    } else {
        u32 pos[4], end[4]; int val[4];
        #pragma unroll
        for (int jj = 0; jj < 4; jj++) {
            if (d[jj] == dcut && cnt[jj] > 0) {
                pos[jj] = off[jj]; end[jj] = off[jj] + cnt[jj];
                val[jj] = (int)bucketList[pos[jj]];
            } else { pos[jj] = 0; end[jj] = 0; val[jj] = 0x7fffffff; }
        }
        for (int it = 0; it < need; it++) {
            int m = min(min(val[0], val[1]), min(val[2], val[3]));
            int g = m;
            #pragma unroll
            for (int s = 32; s >= 1; s >>= 1) g = min(g, __shfl_xor(g, s, 64));
            if (lane == 0) topIdx[q * TOPK + (int)before + it] = g;
            if (m == g && g != 0x7fffffff) {
                #pragma unroll
                for (int jj = 0; jj < 4; jj++) {
                    if (val[jj] == g) {
                        pos[jj]++;
                        val[jj] = (pos[jj] < end[jj]) ? (int)bucketList[pos[jj]] : 0x7fffffff;
                        break;
                    }
                }
            }
        }
    }
}

// ---------------------------------------------------------------------------
// K6: gather + scores + softmax + weighted V sum. Block per query.
// ---------------------------------------------------------------------------
__global__ __launch_bounds__(256) void k_attn(const float* __restrict__ keys,
                                              const float* __restrict__ vals,
                                              const float* __restrict__ query,
                                              const int* __restrict__ topIdx,
                                              float* __restrict__ mo) {
    __shared__ int sIdx[TOPK];
    __shared__ float sSc[TOPK], sE[TOPK];
    int b = blockIdx.x, tid = threadIdx.x;
    if (tid < TOPK) sIdx[tid] = topIdx[b * TOPK + tid];
    __syncthreads();

    int w = tid >> 6, lane = tid & 63;
    const float4* qp = (const float4*)(query + (size_t)b * HID + lane * 8);
    float4 qa = qp[0], qb = qp[1];

    for (int i = w * 8; i < w * 8 + 8; i++) {
        int idx = sIdx[i];
        const float4* kp = (const float4*)(keys + (size_t)idx * HID + lane * 8);
        float4 ka = kp[0], kb = kp[1];
        float dot = qa.x * ka.x + qa.y * ka.y + qa.z * ka.z + qa.w * ka.w
                  + qb.x * kb.x + qb.y * kb.y + qb.z * kb.z + qb.w * kb.w;
        #pragma unroll
        for (int s = 32; s >= 1; s >>= 1) dot += __shfl_xor(dot, s, 64);
        if (lane == 0) sSc[i] = dot * 0.04419417382415922f;  // 1/sqrt(512)
    }
    __syncthreads();

    if (tid < TOPK) {
        float m = -1e30f;
        for (int i = 0; i < TOPK; i++) m = fmaxf(m, sSc[i]);
        sE[tid] = expf(sSc[tid] - m);
    }
    __syncthreads();

    float sum = 0.f;
    for (int i = 0; i < TOPK; i++) sum += sE[i];
    float inv = 1.0f / sum;

    int h0 = tid, h1 = tid + 256;
    float a0 = 0.f, a1 = 0.f;
    for (int i = 0; i < TOPK; i++) {
        int idx = sIdx[i];
        float e = sE[i];
        a0 += e * vals[(size_t)idx * HID + h0];
        a1 += e * vals[(size_t)idx * HID + h1];
    }
    mo[(size_t)b * HID + h0] = a0 * inv;
    mo[(size_t)b * HID + h1] = a1 * inv;
}

// ---------------------------------------------------------------------------
// K7: transpose out_w [o][h] -> wt [h][o] for coalesced projection reads
// ---------------------------------------------------------------------------
__global__ __launch_bounds__(256) void k_transpose(const float* __restrict__ w,
                                                   float* __restrict__ wt) {
    __shared__ float tile[64][65];
    int bx = blockIdx.x, by = blockIdx.y;
    int tx = threadIdx.x & 63, ty = threadIdx.x >> 6;
    for (int r = ty; r < 64; r += 4)
        tile[r][tx] = w[(size_t)(by * 64 + r) * HID + bx * 64 + tx];
    __syncthreads();
    for (int r = ty; r < 64; r += 4)
        wt[(size_t)(bx * 64 + r) * HID + by * 64 + tx] = tile[tx][r];
}

// ---------------------------------------------------------------------------
// K8: out[b][o] = sum_h mo[b][h] * wt[h][o] + bias[o]; 8 b-rows per block.
// ---------------------------------------------------------------------------
__global__ __launch_bounds__(256) void k_proj(const float* __restrict__ mo,
                                              const float* __restrict__ wt,
                                              const float* __restrict__ bias,
                                              float* __restrict__ out) {
    int tid = threadIdx.x;
    int o = (blockIdx.x & 1) * 256 + tid;
    int bb = (blockIdx.x >> 1) * 8;
    float acc[8];
    #pragma unroll
    for (int r = 0; r < 8; r++) acc[r] = 0.f;
    for (int h = 0; h < HID; h++) {
        float wv = wt[(size_t)h * HID + o];
        #pragma unroll
        for (int r = 0; r < 8; r++)
            acc[r] += mo[(size_t)(bb + r) * HID + h] * wv;
    }
    float bv = bias[o];
    #pragma unroll
    for (int r = 0; r < 8; r++)
        out[(size_t)(bb + r) * HID + o] = acc[r] + bv;
}

// ---------------------------------------------------------------------------
extern "C" void kernel_launch(void* const* d_in, const int* in_sizes, int n_in,
                              void* d_out, int out_size, void* d_ws, size_t ws_size,
                              hipStream_t stream) {
    const float* query = (const float*)d_in[0];
    const float* keys  = (const float*)d_in[1];
    const float* vals  = (const float*)d_in[2];
    const float* proj  = (const float*)d_in[3];
    const float* outw  = (const float*)d_in[4];
    const float* outb  = (const float*)d_in[5];
    float* out = (float*)d_out;

    char* ws = (char*)d_ws;
    double*        psumT      = (double*)(ws + 0);              // 32 KB
    unsigned char* qhash      = (unsigned char*)(ws + 32768);   // 2 KB
    unsigned char* khash      = (unsigned char*)(ws + 34816);   // 64 KB
    u32*           hist16     = (u32*)(ws + 100352);            // 16 KB
    u32*           bucketCnt  = (u32*)(ws + 116736);            // 1 KB
    u32*           bucketOff  = (u32*)(ws + 117760);            // 1 KB
    u32*           off16      = (u32*)(ws + 118784);            // 16 KB
    u32*           bucketList = (u32*)(ws + 135168);            // 256 KB
    int*           topIdx     = (int*)(ws + 397312);            // 256 KB
    float*         mo         = (float*)(ws + 659456);          // 4 MB
    float*         wt         = (float*)(ws + 4853760);         // 1 MB
    (void)in_sizes; (void)n_in; (void)out_size; (void)ws_size;

    hipMemsetAsync(hist16, 0, 16384, stream);
    k_psum<<<2, 256, 0, stream>>>(proj, psumT);
    k_hash<<<128, 256, 0, stream>>>(query, BATCH, psumT, qhash, hist16, 0);
    k_hash<<<1024, 256, 0, stream>>>(keys, CAP, psumT, khash, hist16, 1);
    k_scan<<<1, 256, 0, stream>>>(hist16, bucketCnt, bucketOff, off16);
    k_compact<<<1024, 256, 0, stream>>>(khash, off16, bucketList);
    k_select<<<BATCH / 4, 256, 0, stream>>>(qhash, bucketCnt, bucketOff, bucketList, topIdx);
    k_attn<<<BATCH, 256, 0, stream>>>(keys, vals, query, topIdx, mo);
    k_transpose<<<dim3(8, 8), 256, 0, stream>>>(outw, wt);
    k_proj<<<512, 256, 0, stream>>>(mo, wt, outb, out);
}